// Round 5
// baseline (1998.290 us; speedup 1.0000x reference)
//
#include <hip/hip_runtime.h>
#include <stdint.h>

#define T_SEQ 2048

typedef __attribute__((ext_vector_type(8))) short short8;
typedef __attribute__((ext_vector_type(4))) float f32x4;

__device__ __forceinline__ unsigned short f2bf(float f){
  unsigned int u = __float_as_uint(f);
  unsigned int r = u + 0x7fffu + ((u >> 16) & 1u);
  return (unsigned short)(r >> 16);
}
__device__ __forceinline__ float bf2f(unsigned short h){
  return __uint_as_float(((unsigned int)h) << 16);
}
__device__ __forceinline__ float sig_(float x){
  float e = __builtin_amdgcn_exp2f(-1.44269504089f * x);
  return __builtin_amdgcn_rcpf(1.0f + e);
}
__device__ __forceinline__ float tanh_(float x){
  float e = __builtin_amdgcn_exp2f(2.88539008178f * x);
  return 1.0f - 2.0f * __builtin_amdgcn_rcpf(1.0f + e);
}
// Hamilton block value W[qr*64+kr][qc*192+nc]; comp = qr^qc, sign mask 0x5390
__device__ __forceinline__ float ham_val(int qr, int qc, int kr, int nc,
    const float* wr, const float* wi, const float* wj, const float* wk){
  int cc = qr ^ qc;
  const float* w = (cc==0)?wr:(cc==1)?wi:(cc==2)?wj:wk;
  float v = w[kr*192 + nc];
  if ((0x5390u >> (qr*4+qc)) & 1u) v = -v;
  return v;
}

// Build B'^T for the input GEMM: BT[c][k'], c = permuted column, k' in [0,768):
// k'<256 -> hi(W_ih), k' in [256,512) -> lo(W_ih), k'>=512 -> hi(W_ih)
__global__ __launch_bounds__(256) void k_prep_bt(const float* __restrict__ wr,
    const float* __restrict__ wi, const float* __restrict__ wj,
    const float* __restrict__ wk, unsigned short* __restrict__ BT){
  int idx = blockIdx.x*256 + threadIdx.x;       // 768*768
  int c = idx / 768, kp = idx - c*768;
  int kk = kp & 255, piece = kp >> 8;
  int qr = kk >> 6, kr = kk & 63;
  int e = (c/48)*16 + (c & 15);
  int g = (c % 48) >> 4;
  int qc = e >> 6;
  int nc = g*64 + (e & 63);
  float v = ham_val(qr, qc, kr, nc, wr, wi, wj, wk);
  unsigned short hi = f2bf(v);
  unsigned short o = (piece == 1) ? f2bf(v - bf2f(hi)) : hi;
  BT[(size_t)c*768 + kp] = o;
}

// Component-packed W_hh B-fragments of the 4 RAW base matrices.
// Layout: idx = ((w*3+s)*4 + m)*2 + kt (x64 lanes); wave w owns cols
// s*64 + w*16 + u; kt = K-half (chained in-wave in k_rec).
__global__ __launch_bounds__(256) void k_prep_whh(const float* __restrict__ wr,
    const float* __restrict__ wi, const float* __restrict__ wj,
    const float* __restrict__ wk, unsigned short* __restrict__ WF){
  int idx = blockIdx.x*256 + threadIdx.x;       // 24 blocks -> 6144 entries
  int lane = idx & 63;
  int kt = (idx >> 6) & 1;
  int m  = (idx >> 7) & 3;
  int ws3 = idx >> 9;                           // w*3+s, 0..11
  int w = ws3 / 3, s = ws3 - w*3;
  int quad = lane >> 4, u = lane & 15;
  int col = s*64 + w*16 + u;                    // 0..191 (gate*64 + n)
  const float* mat = (m==0)?wr:(m==1)?wi:(m==2)?wj:wk;
  short8 o;
  #pragma unroll
  for (int j = 0; j < 8; j++){
    int k = kt*32 + quad*8 + j;                 // 0..63 (H rows)
    o[j] = (short)f2bf(mat[k*192 + col]);
  }
  *(short8*)(WF + (size_t)idx*8) = o;
}

__global__ __launch_bounds__(256) void k_prep_bias(const float* __restrict__ bih,
    const float* __restrict__ bhh, float* __restrict__ bias){
  int c = blockIdx.x*256 + threadIdx.x;         // 768
  int e = (c/48)*16 + (c & 15);
  int g = (c % 48) >> 4;
  int n = (e >> 6)*192 + g*64 + (e & 63);
  bias[c] = bih[n] + bhh[n];
}

// gi = [x_hi x_hi x_lo] @ [W_hi; W_lo; W_hi] + (b_ih+b_hh), columns permuted.
// 128x128 tile, BK=64, 12 K-chunks. XOR-swizzled LDS (chunk ^= row&7).
__global__ __launch_bounds__(256) void k_gemm_gi(const float* __restrict__ x,
    const unsigned short* __restrict__ BT, const float* __restrict__ bias,
    float* __restrict__ gi){
  __shared__ unsigned short As[128*64];
  __shared__ unsigned short Bs[128*64];
  int tid = threadIdx.x;
  int mb = blockIdx.x / 6, nb = blockIdx.x - mb*6;   // nb fastest: A-slab L2 reuse
  int lane = tid & 63, wid = tid >> 6;
  int quad = lane >> 4, u = lane & 15;
  int wvm = wid >> 1, wvn = wid & 1;
  int srow = tid >> 3, cb = tid & 7;
  f32x4 acc[4][4] = {};
  for (int kc = 0; kc < 12; kc++){
    bool lop = (kc >= 8);
    int kbase = (kc & 3) * 64;
    #pragma unroll
    for (int rd = 0; rd < 4; rd++){
      int m = rd*32 + srow;
      int lc = cb ^ (m & 7);
      const float* xp = x + (size_t)(mb*128 + m)*256 + kbase + lc*8;
      float4 v0 = *(const float4*)xp;
      float4 v1 = *(const float4*)(xp + 4);
      float vv[8] = {v0.x, v0.y, v0.z, v0.w, v1.x, v1.y, v1.z, v1.w};
      short8 ov;
      #pragma unroll
      for (int q = 0; q < 8; q++){
        unsigned short hi = f2bf(vv[q]);
        ov[q] = (short)(lop ? f2bf(vv[q] - bf2f(hi)) : hi);
      }
      *(short8*)&As[m*64 + cb*8] = ov;
    }
    #pragma unroll
    for (int rd = 0; rd < 4; rd++){
      int c = rd*32 + srow;
      int lc = cb ^ (c & 7);
      const unsigned short* bp = BT + (size_t)(nb*128 + c)*768 + kc*64 + lc*8;
      *(short8*)&Bs[c*64 + cb*8] = *(const short8*)bp;
    }
    __syncthreads();
    #pragma unroll
    for (int ks = 0; ks < 2; ks++){
      short8 af[4], bf[4];
      #pragma unroll
      for (int i=0;i<4;i++){
        int row = 64*wvm + 16*i + u;
        af[i] = *(const short8*)&As[row*64 + ((4*ks+quad) ^ (u & 7))*8];
      }
      #pragma unroll
      for (int j=0;j<4;j++){
        int row = 64*wvn + 16*j + u;
        bf[j] = *(const short8*)&Bs[row*64 + ((4*ks+quad) ^ (u & 7))*8];
      }
      #pragma unroll
      for (int i=0;i<4;i++)
        #pragma unroll
        for (int j=0;j<4;j++)
          acc[i][j] = __builtin_amdgcn_mfma_f32_16x16x32_bf16(af[i], bf[j], acc[i][j], 0, 0, 0);
    }
    __syncthreads();
  }
  int cb2 = nb*128 + 64*wvn;
  #pragma unroll
  for (int j=0;j<4;j++){
    float bj = bias[cb2 + 16*j + u];
    #pragma unroll
    for (int i=0;i<4;i++){
      float* gp = gi + (size_t)(mb*128 + 64*wvm + 16*i + quad*4)*768 + cb2 + 16*j + u;
      #pragma unroll
      for (int r=0;r<4;r++)
        gp[(size_t)r*768] = acc[i][j][r] + bj;
    }
  }
}

// Recurrence: 1 WG = TWO batch chains, 4 waves (256 thr), 1 wave/SIMD.
// Two independent dependency chains per wave (batch A, batch B): while one
// batch's combine/sigmoid/tanh chain waits, the other batch's 24 MFMAs keep
// the matrix pipe fed (in-wave interleave; MFMA issue slot ~4cyc vs 19.4cyc
// pipe occupancy). Per-SIMD per step: 48 MFMA (932cyc) serving 2 batches.
// hbuf rows padded to 88 elems: A-read banks = (12*sigma + 4*quad) % 32 ->
// 2-way aliasing (free) instead of 16-way conflict; 16B alignment kept
// (sigma*176B). One raw barrier/step, bracketed by memory clobbers
// (s_barrier is IntrNoMem; loads would hoist above it otherwise).
// A rows use permutation sigma(row)=(row&3)^(row>>2) so the Hamilton
// combine is the acc diagonal with per-lane +-1 signs (no divergence):
//   o_s = acc[4s+0][0] + sg1*acc[4s+1][1] + sg2*acc[4s+2][2] + sg3*acc[4s+3][3]
// sg_r = sign(r^quad, quad) from mask 0x5390.
// gi prefetch: depth-4 rotating register sets (x4 unroll, static indices);
// prefetch address clamped to gi's last row (values past t=2047 never used).
__global__ __launch_bounds__(256, 1) void k_rec(const float* __restrict__ gi,
    const short8* __restrict__ WF, const float* __restrict__ hx,
    float* __restrict__ out){
  __shared__ unsigned short hbuf[2][2][4][88];  // [phase][batch][comp][64+24 pad]
  int tid = threadIdx.x;
  int b0 = blockIdx.x * 2;
  int lane = tid & 63, w = tid >> 6;
  int quad = lane >> 4, u = lane & 15;
  short8 Bf[12][2];                             // [s*4+m][kt] : 96 VGPRs (shared by both batches)
  #pragma unroll
  for (int s = 0; s < 3; s++)
    #pragma unroll
    for (int m = 0; m < 4; m++)
      #pragma unroll
      for (int kt = 0; kt < 2; kt++)
        Bf[s*4+m][kt] = WF[(size_t)((((w*3+s)*4+m)*2+kt)*64 + lane)];
  int sg = (u & 3) ^ (u >> 2);                  // sigma(u): A row u holds h_sigma(u)
  int abase = sg*88 + quad*8;                   // elem offset within [batch] block
  float sg1 = (quad & 1)              ?  1.f : -1.f;
  float sg2 = (quad==1 || quad==2)    ?  1.f : -1.f;
  float sg3 = (quad >> 1)             ?  1.f : -1.f;
  int e = quad*64 + w*16 + u;                   // comp*64 + n
  int wbase = quad*88 + w*16 + u;               // write elem offset within [batch] block
  unsigned short* hb = &hbuf[0][0][0][0];       // phase stride 704 elems, batch stride 352
  float hA = hx[b0*256 + e];
  float hB = hx[b0*256 + 256 + e];
  hb[wbase]       = f2bf(hA);
  hb[352 + wbase] = f2bf(hB);
  // gi column for (e, gate g): c = (e>>4)*48 + g*16 + (e&15)
  const float* glA = gi + (size_t)b0*768 + (quad*4 + w)*48 + u;
  const float* glB = glA + 768;
  float* outA = out + (size_t)b0*256 + e;
  float* outB = outA + 256;
  float pfA[4][3], pfB[4][3];
  #pragma unroll
  for (int j = 0; j < 4; j++){
    const float* pA = glA + (size_t)j*49152;
    const float* pB = glB + (size_t)j*49152;
    pfA[j][0]=pA[0]; pfA[j][1]=pA[16]; pfA[j][2]=pA[32];
    pfB[j][0]=pB[0]; pfB[j][1]=pB[16]; pfB[j][2]=pB[32];
  }
  const float* gpA = glA + (size_t)4*49152;
  const float* gpB = glB + (size_t)4*49152;
  const float* glastA = glA + (size_t)(T_SEQ-1)*49152;
  const float* glastB = glB + (size_t)(T_SEQ-1)*49152;
  asm volatile("s_waitcnt lgkmcnt(0)" ::: "memory");
  __builtin_amdgcn_s_barrier();
  asm volatile("" ::: "memory");
  for (int t0 = 0; t0 < T_SEQ; t0 += 4){
    #pragma unroll
    for (int j = 0; j < 4; j++){
      int ph = j & 1;
      const unsigned short* ha = hb + ph*704;
      short8 a0A = *(const short8*)&ha[abase];
      short8 a1A = *(const short8*)&ha[abase + 32];
      short8 a0B = *(const short8*)&ha[352 + abase];
      short8 a1B = *(const short8*)&ha[352 + abase + 32];
      f32x4 accA[12], accB[12];
      // batch A: kt0 burst then kt1 burst (12 indep chains of 2)
      #pragma unroll
      for (int sm = 0; sm < 12; sm++)
        accA[sm] = __builtin_amdgcn_mfma_f32_16x16x32_bf16(a0A, Bf[sm][0],
                     (f32x4){0.f,0.f,0.f,0.f}, 0, 0, 0);
      #pragma unroll
      for (int sm = 0; sm < 12; sm++)
        accA[sm] = __builtin_amdgcn_mfma_f32_16x16x32_bf16(a1A, Bf[sm][1],
                     accA[sm], 0, 0, 0);
      // batch B: its MFMAs issue while batch A's combine/gate chain runs
      #pragma unroll
      for (int sm = 0; sm < 12; sm++)
        accB[sm] = __builtin_amdgcn_mfma_f32_16x16x32_bf16(a0B, Bf[sm][0],
                     (f32x4){0.f,0.f,0.f,0.f}, 0, 0, 0);
      #pragma unroll
      for (int sm = 0; sm < 12; sm++)
        accB[sm] = __builtin_amdgcn_mfma_f32_16x16x32_bf16(a1B, Bf[sm][1],
                     accB[sm], 0, 0, 0);
      int t = t0 + j;
      {
        float o0 = accA[0][0] + sg1*accA[1][1] + sg2*accA[2][2]  + sg3*accA[3][3];
        float o1 = accA[4][0] + sg1*accA[5][1] + sg2*accA[6][2]  + sg3*accA[7][3];
        float o2 = accA[8][0] + sg1*accA[9][1] + sg2*accA[10][2] + sg3*accA[11][3];
        float r  = sig_(pfA[j][0] + o0);
        float z  = sig_(pfA[j][1] + o1);
        float nn = tanh_(pfA[j][2] + r * o2);
        hA = nn + z * (hA - nn);
        outA[(size_t)t * 16384] = hA;
        hb[(ph^1)*704 + wbase] = f2bf(hA);
        const float* pv = (gpA <= glastA) ? gpA : glastA;
        pfA[j][0] = pv[0]; pfA[j][1] = pv[16]; pfA[j][2] = pv[32];
        gpA += 49152;
      }
      {
        float o0 = accB[0][0] + sg1*accB[1][1] + sg2*accB[2][2]  + sg3*accB[3][3];
        float o1 = accB[4][0] + sg1*accB[5][1] + sg2*accB[6][2]  + sg3*accB[7][3];
        float o2 = accB[8][0] + sg1*accB[9][1] + sg2*accB[10][2] + sg3*accB[11][3];
        float r  = sig_(pfB[j][0] + o0);
        float z  = sig_(pfB[j][1] + o1);
        float nn = tanh_(pfB[j][2] + r * o2);
        hB = nn + z * (hB - nn);
        outB[(size_t)t * 16384] = hB;
        hb[(ph^1)*704 + 352 + wbase] = f2bf(hB);
        const float* pv = (gpB <= glastB) ? gpB : glastB;
        pfB[j][0] = pv[0]; pfB[j][1] = pv[16]; pfB[j][2] = pv[32];
        gpB += 49152;
      }
      asm volatile("s_waitcnt lgkmcnt(0)" ::: "memory");
      __builtin_amdgcn_s_barrier();
      asm volatile("" ::: "memory");
    }
  }
  out[(size_t)T_SEQ * 16384 + b0*256 + e] = hA;
  out[(size_t)T_SEQ * 16384 + b0*256 + 256 + e] = hB;
}

extern "C" void kernel_launch(void* const* d_in, const int* in_sizes, int n_in,
                              void* d_out, int out_size, void* d_ws, size_t ws_size,
                              hipStream_t stream){
  const float* x    = (const float*)d_in[0];
  const float* hx   = (const float*)d_in[1];
  const float* wihr = (const float*)d_in[2];
  const float* wihi = (const float*)d_in[3];
  const float* wihj = (const float*)d_in[4];
  const float* wihk = (const float*)d_in[5];
  const float* whhr = (const float*)d_in[6];
  const float* whhi = (const float*)d_in[7];
  const float* whhj = (const float*)d_in[8];
  const float* whhk = (const float*)d_in[9];
  const float* bih  = (const float*)d_in[10];
  const float* bhh  = (const float*)d_in[11];
  char* ws = (char*)d_ws;
  float* gi          = (float*)ws;                            // 402,653,184 B
  unsigned short* BT = (unsigned short*)(ws + 402653184ull);  //   1,179,648 B
  unsigned short* WF = (unsigned short*)(ws + 403832832ull);  //      98,304 B
  float* bias        = (float*)(ws + 404226048ull);           //       3,072 B
  k_prep_bt  <<<dim3(2304), dim3(256), 0, stream>>>(wihr, wihi, wihj, wihk, BT);
  k_prep_whh <<<dim3(24),   dim3(256), 0, stream>>>(whhr, whhi, whhj, whhk, WF);
  k_prep_bias<<<dim3(3),    dim3(256), 0, stream>>>(bih, bhh, bias);
  k_gemm_gi  <<<dim3(6144), dim3(256), 0, stream>>>(x, BT, bias, gi);
  k_rec      <<<dim3(32),   dim3(256), 0, stream>>>(gi, (const short8*)WF, hx, (float*)d_out);
}

// Round 6
// 1518.451 us; speedup vs baseline: 1.3160x; 1.3160x over previous
//
#include <hip/hip_runtime.h>
#include <stdint.h>

#define T_SEQ 2048

typedef __attribute__((ext_vector_type(8))) short short8;
typedef __attribute__((ext_vector_type(4))) float f32x4;

__device__ __forceinline__ unsigned short f2bf(float f){
  unsigned int u = __float_as_uint(f);
  unsigned int r = u + 0x7fffu + ((u >> 16) & 1u);
  return (unsigned short)(r >> 16);
}
__device__ __forceinline__ float bf2f(unsigned short h){
  return __uint_as_float(((unsigned int)h) << 16);
}
__device__ __forceinline__ float sig_(float x){
  float e = __builtin_amdgcn_exp2f(-1.44269504089f * x);
  return __builtin_amdgcn_rcpf(1.0f + e);
}
__device__ __forceinline__ float tanh_(float x){
  float e = __builtin_amdgcn_exp2f(2.88539008178f * x);
  return 1.0f - 2.0f * __builtin_amdgcn_rcpf(1.0f + e);
}
// Hamilton block value W[qr*64+kr][qc*192+nc]; comp = qr^qc, sign mask 0x5390
__device__ __forceinline__ float ham_val(int qr, int qc, int kr, int nc,
    const float* wr, const float* wi, const float* wj, const float* wk){
  int cc = qr ^ qc;
  const float* w = (cc==0)?wr:(cc==1)?wi:(cc==2)?wj:wk;
  float v = w[kr*192 + nc];
  if ((0x5390u >> (qr*4+qc)) & 1u) v = -v;
  return v;
}

// Build B'^T for the input GEMM: BT[c][k'], c = permuted column, k' in [0,768):
// k'<256 -> hi(W_ih), k' in [256,512) -> lo(W_ih), k'>=512 -> hi(W_ih)
__global__ __launch_bounds__(256) void k_prep_bt(const float* __restrict__ wr,
    const float* __restrict__ wi, const float* __restrict__ wj,
    const float* __restrict__ wk, unsigned short* __restrict__ BT){
  int idx = blockIdx.x*256 + threadIdx.x;       // 768*768
  int c = idx / 768, kp = idx - c*768;
  int kk = kp & 255, piece = kp >> 8;
  int qr = kk >> 6, kr = kk & 63;
  int e = (c/48)*16 + (c & 15);
  int g = (c % 48) >> 4;
  int qc = e >> 6;
  int nc = g*64 + (e & 63);
  float v = ham_val(qr, qc, kr, nc, wr, wi, wj, wk);
  unsigned short hi = f2bf(v);
  unsigned short o = (piece == 1) ? f2bf(v - bf2f(hi)) : hi;
  BT[(size_t)c*768 + kp] = o;
}

// Component-packed W_hh B-fragments of the 4 RAW base matrices.
// Layout: idx = ((w*3+s)*4 + m)*2 + kt (x64 lanes); wave w owns cols
// s*64 + w*16 + u; kt = K-half (chained in-wave in k_rec).
__global__ __launch_bounds__(256) void k_prep_whh(const float* __restrict__ wr,
    const float* __restrict__ wi, const float* __restrict__ wj,
    const float* __restrict__ wk, unsigned short* __restrict__ WF){
  int idx = blockIdx.x*256 + threadIdx.x;       // 24 blocks -> 6144 entries
  int lane = idx & 63;
  int kt = (idx >> 6) & 1;
  int m  = (idx >> 7) & 3;
  int ws3 = idx >> 9;                           // w*3+s, 0..11
  int w = ws3 / 3, s = ws3 - w*3;
  int quad = lane >> 4, u = lane & 15;
  int col = s*64 + w*16 + u;                    // 0..191 (gate*64 + n)
  const float* mat = (m==0)?wr:(m==1)?wi:(m==2)?wj:wk;
  short8 o;
  #pragma unroll
  for (int j = 0; j < 8; j++){
    int k = kt*32 + quad*8 + j;                 // 0..63 (H rows)
    o[j] = (short)f2bf(mat[k*192 + col]);
  }
  *(short8*)(WF + (size_t)idx*8) = o;
}

__global__ __launch_bounds__(256) void k_prep_bias(const float* __restrict__ bih,
    const float* __restrict__ bhh, float* __restrict__ bias){
  int c = blockIdx.x*256 + threadIdx.x;         // 768
  int e = (c/48)*16 + (c & 15);
  int g = (c % 48) >> 4;
  int n = (e >> 6)*192 + g*64 + (e & 63);
  bias[c] = bih[n] + bhh[n];
}

// gi = [x_hi x_hi x_lo] @ [W_hi; W_lo; W_hi] + (b_ih+b_hh), columns permuted.
// 128x128 tile, BK=64, 12 K-chunks. XOR-swizzled LDS (chunk ^= row&7).
__global__ __launch_bounds__(256) void k_gemm_gi(const float* __restrict__ x,
    const unsigned short* __restrict__ BT, const float* __restrict__ bias,
    float* __restrict__ gi){
  __shared__ unsigned short As[128*64];
  __shared__ unsigned short Bs[128*64];
  int tid = threadIdx.x;
  int mb = blockIdx.x / 6, nb = blockIdx.x - mb*6;   // nb fastest: A-slab L2 reuse
  int lane = tid & 63, wid = tid >> 6;
  int quad = lane >> 4, u = lane & 15;
  int wvm = wid >> 1, wvn = wid & 1;
  int srow = tid >> 3, cb = tid & 7;
  f32x4 acc[4][4] = {};
  for (int kc = 0; kc < 12; kc++){
    bool lop = (kc >= 8);
    int kbase = (kc & 3) * 64;
    #pragma unroll
    for (int rd = 0; rd < 4; rd++){
      int m = rd*32 + srow;
      int lc = cb ^ (m & 7);
      const float* xp = x + (size_t)(mb*128 + m)*256 + kbase + lc*8;
      float4 v0 = *(const float4*)xp;
      float4 v1 = *(const float4*)(xp + 4);
      float vv[8] = {v0.x, v0.y, v0.z, v0.w, v1.x, v1.y, v1.z, v1.w};
      short8 ov;
      #pragma unroll
      for (int q = 0; q < 8; q++){
        unsigned short hi = f2bf(vv[q]);
        ov[q] = (short)(lop ? f2bf(vv[q] - bf2f(hi)) : hi);
      }
      *(short8*)&As[m*64 + cb*8] = ov;
    }
    #pragma unroll
    for (int rd = 0; rd < 4; rd++){
      int c = rd*32 + srow;
      int lc = cb ^ (c & 7);
      const unsigned short* bp = BT + (size_t)(nb*128 + c)*768 + kc*64 + lc*8;
      *(short8*)&Bs[c*64 + cb*8] = *(const short8*)bp;
    }
    __syncthreads();
    #pragma unroll
    for (int ks = 0; ks < 2; ks++){
      short8 af[4], bf[4];
      #pragma unroll
      for (int i=0;i<4;i++){
        int row = 64*wvm + 16*i + u;
        af[i] = *(const short8*)&As[row*64 + ((4*ks+quad) ^ (u & 7))*8];
      }
      #pragma unroll
      for (int j=0;j<4;j++){
        int row = 64*wvn + 16*j + u;
        bf[j] = *(const short8*)&Bs[row*64 + ((4*ks+quad) ^ (u & 7))*8];
      }
      #pragma unroll
      for (int i=0;i<4;i++)
        #pragma unroll
        for (int j=0;j<4;j++)
          acc[i][j] = __builtin_amdgcn_mfma_f32_16x16x32_bf16(af[i], bf[j], acc[i][j], 0, 0, 0);
    }
    __syncthreads();
  }
  int cb2 = nb*128 + 64*wvn;
  #pragma unroll
  for (int j=0;j<4;j++){
    float bj = bias[cb2 + 16*j + u];
    #pragma unroll
    for (int i=0;i<4;i++){
      float* gp = gi + (size_t)(mb*128 + 64*wvm + 16*i + quad*4)*768 + cb2 + 16*j + u;
      #pragma unroll
      for (int r=0;r<4;r++)
        gp[(size_t)r*768] = acc[i][j][r] + bj;
    }
  }
}

// Recurrence: 1 WG = 1 batch chain, 4 waves (256 thr), 1 wave/SIMD (r4 base).
// Round-6 deltas vs r4:
//  (1) XOR granule-swizzled hbuf (16B granules; block q: gran ^= 2q on write,
//      gran ^= 2*sigma on read). A-reads: 4-way bank conflict -> 2-way (free);
//      writes conflict-free. Lane-constant addresses, zero runtime cost.
//  (2) out-store + gi prefetch moved AFTER the barrier into the ds_read
//      latency shadow (r4 pinned them between ds_write and barrier via the
//      "memory" clobbers -> serial issue cost).
//  (3) MFMA groups ordered by gate (s0,s1 -> o0+sig r -> s2 -> o1,o2) so the
//      reset-gate transcendental overlaps s2's MFMA issue; h->bf16 via
//      v_cvt_pk_bf16_f32 (RNE, bit-identical to f2bf).
// A rows use permutation sigma(row)=(row&3)^(row>>2) so the Hamilton combine
// is the acc diagonal with per-lane +-1 signs (no divergence); sg_r from
// mask 0x5390. One raw barrier/step bracketed by memory clobbers (s_barrier
// is IntrNoMem - loads would hoist above it otherwise).
__global__ __launch_bounds__(256, 1) void k_rec(const float* __restrict__ gi,
    const short8* __restrict__ WF, const float* __restrict__ hx,
    float* __restrict__ out){
  __shared__ unsigned short hbuf[2][256];
  int tid = threadIdx.x;
  int b = blockIdx.x;
  int lane = tid & 63, w = tid >> 6;
  int quad = lane >> 4, u = lane & 15;
  short8 Bf[12][2];                             // [s*4+m][kt] (lives in AGPRs)
  #pragma unroll
  for (int s = 0; s < 3; s++)
    #pragma unroll
    for (int m = 0; m < 4; m++)
      #pragma unroll
      for (int kt = 0; kt < 2; kt++)
        Bf[s*4+m][kt] = WF[(size_t)((((w*3+s)*4+m)*2+kt)*64 + lane)];
  int sg = (u & 3) ^ (u >> 2);                  // sigma(u): A row u holds h_sigma(u)
  // swizzled read offsets: logical granule sg*8 + q (a0) / sg*8 + q+4 (a1),
  // phys granule = sg*8 + (o ^ 2*sg)
  int a0off = sg*64 + ((quad ^ (2*sg)) & 7)*8;
  int a1off = sg*64 + (((quad + 4) ^ (2*sg)) & 7)*8;
  float sg1 = (quad & 1)              ?  1.f : -1.f;
  float sg2 = (quad==1 || quad==2)    ?  1.f : -1.f;
  float sg3 = (quad >> 1)             ?  1.f : -1.f;
  int e = quad*64 + w*16 + u;                   // comp*64 + n
  // swizzled write offset: logical granule quad*8 + (w*2 + u>>3), phys o ^= 2*quad
  int wboff = quad*64 + (((w*2 + (u>>3)) ^ (2*quad)) & 7)*8 + (u & 7);
  float h = hx[b*256 + e];
  hbuf[0][wboff] = f2bf(h);
  // gi column for (e, gate g): c = (e>>4)*48 + g*16 + (e&15)
  const float* gl = gi + (size_t)b*768 + (quad*4 + w)*48 + u;
  float* outp = out + (size_t)b*256 + e;
  float pf[4][3];
  #pragma unroll
  for (int j = 0; j < 4; j++){
    const float* p = gl + (size_t)j*49152;
    pf[j][0] = p[0]; pf[j][1] = p[16]; pf[j][2] = p[32];
  }
  const float* gp    = gl + (size_t)4*49152;
  const float* glast = gl + (size_t)(T_SEQ-1)*49152;
  asm volatile("s_waitcnt lgkmcnt(0)" ::: "memory");
  __builtin_amdgcn_s_barrier();
  asm volatile("" ::: "memory");
  for (int t0 = 0; t0 < T_SEQ; t0 += 4){
    #pragma unroll
    for (int j = 0; j < 4; j++){
      int ph = j & 1;
      const unsigned short* hb = hbuf[ph];
      // (a) issue ds_reads first; everything below fills their ~120cy shadow
      short8 a0 = *(const short8*)&hb[a0off];
      short8 a1 = *(const short8*)&hb[a1off];
      // (b) store previous step's h (h(t-1)) in the shadow
      if (t0 + j > 0)
        outp[(size_t)(t0 + j - 1) * 16384] = h;
      // (c) consume old prefetch into locals, then issue loads for t+4
      float g0 = pf[j][0], g1 = pf[j][1], g2 = pf[j][2];
      const float* pv = (gp <= glast) ? gp : glast;   // clamp: stay inside gi
      pf[j][0] = pv[0]; pf[j][1] = pv[16]; pf[j][2] = pv[32];
      gp += 49152;
      // (d) MFMAs: gate s0, s1 first
      f32x4 acc[12];
      #pragma unroll
      for (int sm = 0; sm < 8; sm++)
        acc[sm] = __builtin_amdgcn_mfma_f32_16x16x32_bf16(a0, Bf[sm][0],
                    (f32x4){0.f,0.f,0.f,0.f}, 0, 0, 0);
      #pragma unroll
      for (int sm = 0; sm < 8; sm++)
        acc[sm] = __builtin_amdgcn_mfma_f32_16x16x32_bf16(a1, Bf[sm][1],
                    acc[sm], 0, 0, 0);
      // (e) o0 + reset gate overlap gate-s2 MFMA issue
      float o0 = acc[0][0] + sg1*acc[1][1] + sg2*acc[2][2]  + sg3*acc[3][3];
      float r  = sig_(g0 + o0);
      #pragma unroll
      for (int sm = 8; sm < 12; sm++)
        acc[sm] = __builtin_amdgcn_mfma_f32_16x16x32_bf16(a0, Bf[sm][0],
                    (f32x4){0.f,0.f,0.f,0.f}, 0, 0, 0);
      #pragma unroll
      for (int sm = 8; sm < 12; sm++)
        acc[sm] = __builtin_amdgcn_mfma_f32_16x16x32_bf16(a1, Bf[sm][1],
                    acc[sm], 0, 0, 0);
      float o1 = acc[4][0] + sg1*acc[5][1] + sg2*acc[6][2]  + sg3*acc[7][3];
      float z  = sig_(g1 + o1);
      float o2 = acc[8][0] + sg1*acc[9][1] + sg2*acc[10][2] + sg3*acc[11][3];
      float nn = tanh_(g2 + r * o2);
      h = nn + z * (h - nn);
      unsigned int hpk;
      asm("v_cvt_pk_bf16_f32 %0, %1, %2" : "=v"(hpk) : "v"(h), "v"(h));
      hbuf[ph ^ 1][wboff] = (unsigned short)hpk;
      asm volatile("s_waitcnt lgkmcnt(0)" ::: "memory");
      __builtin_amdgcn_s_barrier();
      asm volatile("" ::: "memory");
    }
  }
  outp[(size_t)(T_SEQ - 1) * 16384] = h;
  out[(size_t)T_SEQ * 16384 + b*256 + e] = h;
}

extern "C" void kernel_launch(void* const* d_in, const int* in_sizes, int n_in,
                              void* d_out, int out_size, void* d_ws, size_t ws_size,
                              hipStream_t stream){
  const float* x    = (const float*)d_in[0];
  const float* hx   = (const float*)d_in[1];
  const float* wihr = (const float*)d_in[2];
  const float* wihi = (const float*)d_in[3];
  const float* wihj = (const float*)d_in[4];
  const float* wihk = (const float*)d_in[5];
  const float* whhr = (const float*)d_in[6];
  const float* whhi = (const float*)d_in[7];
  const float* whhj = (const float*)d_in[8];
  const float* whhk = (const float*)d_in[9];
  const float* bih  = (const float*)d_in[10];
  const float* bhh  = (const float*)d_in[11];
  char* ws = (char*)d_ws;
  float* gi          = (float*)ws;                            // 402,653,184 B
  unsigned short* BT = (unsigned short*)(ws + 402653184ull);  //   1,179,648 B
  unsigned short* WF = (unsigned short*)(ws + 403832832ull);  //      98,304 B
  float* bias        = (float*)(ws + 404226048ull);           //       3,072 B
  k_prep_bt  <<<dim3(2304), dim3(256), 0, stream>>>(wihr, wihi, wihj, wihk, BT);
  k_prep_whh <<<dim3(24),   dim3(256), 0, stream>>>(whhr, whhi, whhj, whhk, WF);
  k_prep_bias<<<dim3(3),    dim3(256), 0, stream>>>(bih, bhh, bias);
  k_gemm_gi  <<<dim3(6144), dim3(256), 0, stream>>>(x, BT, bias, gi);
  k_rec      <<<dim3(64),   dim3(256), 0, stream>>>(gi, (const short8*)WF, hx, (float*)d_out);
}